// Round 12
// baseline (237.448 us; speedup 1.0000x reference)
//
#include <hip/hip_runtime.h>
#include <stdint.h>

#define NTOK 16384
#define CDIM 1024
#define DHEAD 256

typedef short s16x8 __attribute__((ext_vector_type(8)));
typedef unsigned short u16x8 __attribute__((ext_vector_type(8)));
typedef _Float16 h16x8 __attribute__((ext_vector_type(8)));
typedef float f32x4 __attribute__((ext_vector_type(4)));
typedef float f32x16 __attribute__((ext_vector_type(16)));

static __device__ __forceinline__ unsigned short f2bf(float f) {
    union { float f; unsigned u; } x; x.f = f;
    unsigned r = (x.u + 0x7fffu + ((x.u >> 16) & 1u)) >> 16;
    return (unsigned short)r;
}
static __device__ __forceinline__ unsigned short f2h(float f) {
    _Float16 h = (_Float16)f;
    return __builtin_bit_cast(unsigned short, h);
}
static __device__ __forceinline__ unsigned cvtpk(float lo, float hi) {
    unsigned r;
    asm("v_cvt_pk_bf16_f32 %0, %1, %2" : "=v"(r) : "v"(lo), "v"(hi));
    return r;
}
// Barrier ordering LDS only — global loads stay in flight across it (T4).
static __device__ __forceinline__ void lgkm_barrier() {
    asm volatile("s_waitcnt lgkmcnt(0)" ::: "memory");
    __builtin_amdgcn_s_barrier();
}

// ---------------------------------------------------------------------------
// Kernel 1: partial Gram G[de][e] over an n-chunk + per-channel sums.
// DEMAND-MINIMAL at R11's ceiling flow: tile 256(de) x 128(e), es-split x2
// (R11's x4 split re-read q 4x -> 673 MB demand; this is 418 MB. Measured
// invariant: every design delivers ~6.4 TB/s of L1-level demand, so time
// scales with demand bytes).
// 8 waves, wave-tile 64x64 -> acc[2][2] = 64 AGPR; unified ~120 < 128 cap
// at launch_bounds(512,4) -> 2 blocks/CU (R11-proven flow).
// Staging roles: t<256 q (64 quads x 4 rowgrps), t in [256,384) k (32 quads).
// Depth-2 register sets, 16-row stages, lgkm-only barriers.
// Co-XCD: XCD = chunk%8 for all (b,h,es) of a chunk (nchunk%8==0) -> L2 dedup.
// ---------------------------------------------------------------------------
__global__ __launch_bounds__(512, 4)
void k_gram(const float* __restrict__ q, const float* __restrict__ k,
            unsigned short* __restrict__ Gpart, float* __restrict__ Spart, int nchunk)
{
    __shared__ __align__(16) ushort4 lq4[4 * 256];   // 8 KB [rowquad][ch^rq]
    __shared__ __align__(16) ushort4 lk4[4 * 128];   // 4 KB

    const int P   = blockIdx.x;
    const int t8  = P & 7;
    const int es  = (P >> 3) & 1;
    const int thi = P >> 4;
    const int T   = thi * 8 + t8;            // bh*nchunk + chunk
    const int bh  = T / nchunk;
    const int chunk = T - bh * nchunk;
    const int b = bh >> 2, h = bh & 3;
    const int rows = NTOK / nchunk;
    const int S    = rows >> 4;              // 16-row stages
    const int n0c  = chunk * rows;

    const int t = threadIdx.x;
    const int lane = t & 63, w = t >> 6;
    const int l31 = lane & 31, g2 = lane >> 5;
    const int wr = w >> 1, wc = w & 1;       // de-group*64, e-group*64

    const bool qt = t < 256;
    const bool kt = (t >= 256) && (t < 384);
    const int qcq = t >> 2, qrg = t & 3;     // q: quad 0..63, rowgrp 0..3
    const int kid = t - 256;
    const int kcq = kid >> 2, krg = kid & 3; // k: quad 0..31, rowgrp 0..3

    const float* qp = q + ((size_t)(b * NTOK + n0c + qrg * 4)) * CDIM + h * DHEAD + qcq * 4;
    const float* kp = k + ((size_t)(b * NTOK + n0c + krg * 4)) * CDIM + h * DHEAD + es * 128 + kcq * 4;

    f32x4 sgA[4], sgB[4];
#define LOADSET(dst, s) do {                                                   \
        if (qt) { _Pragma("unroll") for (int j_ = 0; j_ < 4; ++j_)              \
            dst[j_] = *reinterpret_cast<const f32x4*>(qp + ((size_t)(s) * 16 + j_) * CDIM); } \
        else if (kt) { _Pragma("unroll") for (int j_ = 0; j_ < 4; ++j_)         \
            dst[j_] = *reinterpret_cast<const f32x4*>(kp + ((size_t)(s) * 16 + j_) * CDIM); } \
    } while (0)

    float ssum[4] = {0.f, 0.f, 0.f, 0.f};
#define CONSUME(src) do {                                                      \
        if (qt) {                                                               \
            _Pragma("unroll") for (int c_ = 0; c_ < 4; ++c_) {                  \
                const int ch_ = qcq * 4 + c_;                                   \
                ushort4 p_;                                                     \
                p_.x = f2bf(src[0][c_]); p_.y = f2bf(src[1][c_]);               \
                p_.z = f2bf(src[2][c_]); p_.w = f2bf(src[3][c_]);               \
                ssum[c_] += (src[0][c_] + src[1][c_]) + (src[2][c_] + src[3][c_]); \
                lq4[qrg * 256 + (ch_ ^ qrg)] = p_;                              \
            }                                                                   \
        } else if (kt) {                                                        \
            _Pragma("unroll") for (int c_ = 0; c_ < 4; ++c_) {                  \
                const int ch_ = kcq * 4 + c_;                                   \
                ushort4 p_;                                                     \
                p_.x = f2bf(src[0][c_]); p_.y = f2bf(src[1][c_]);               \
                p_.z = f2bf(src[2][c_]); p_.w = f2bf(src[3][c_]);               \
                ssum[c_] += (src[0][c_] + src[1][c_]) + (src[2][c_] + src[3][c_]); \
                lk4[krg * 128 + (ch_ ^ krg)] = p_;                              \
            }                                                                   \
        }                                                                       \
    } while (0)

    f32x16 acc[2][2];
#pragma unroll
    for (int r = 0; r < 2; ++r)
#pragma unroll
        for (int c = 0; c < 2; ++c)
#pragma unroll
            for (int j = 0; j < 16; ++j) acc[r][c][j] = 0.f;

    const uint2* lqu = reinterpret_cast<const uint2*>(lq4);
    const uint2* lku = reinterpret_cast<const uint2*>(lk4);
    const int gLo = 2 * g2, gHi = 2 * g2 + 1;

#define MFMAPHASE() do {                                                       \
        s16x8 af_[2], bf_[2];                                                  \
        _Pragma("unroll") for (int r_ = 0; r_ < 2; ++r_) {                     \
            const int ch_ = wr * 64 + r_ * 32 + l31;                           \
            const uint2 lo_ = lqu[gLo * 256 + (ch_ ^ gLo)];                    \
            const uint2 hi_ = lqu[gHi * 256 + (ch_ ^ gHi)];                    \
            int4 f_; f_.x = lo_.x; f_.y = lo_.y; f_.z = hi_.x; f_.w = hi_.y;   \
            af_[r_] = __builtin_bit_cast(s16x8, f_);                           \
        }                                                                       \
        _Pragma("unroll") for (int c_ = 0; c_ < 2; ++c_) {                     \
            const int ch_ = wc * 64 + c_ * 32 + l31;                           \
            const uint2 lo_ = lku[gLo * 128 + (ch_ ^ gLo)];                    \
            const uint2 hi_ = lku[gHi * 128 + (ch_ ^ gHi)];                    \
            int4 f_; f_.x = lo_.x; f_.y = lo_.y; f_.z = hi_.x; f_.w = hi_.y;   \
            bf_[c_] = __builtin_bit_cast(s16x8, f_);                           \
        }                                                                       \
        _Pragma("unroll") for (int r_ = 0; r_ < 2; ++r_)                       \
            _Pragma("unroll") for (int c_ = 0; c_ < 2; ++c_)                   \
                acc[r_][c_] = __builtin_amdgcn_mfma_f32_32x32x16_bf16(         \
                    af_[r_], bf_[c_], acc[r_][c_], 0, 0, 0);                   \
    } while (0)

    LOADSET(sgA, 0);
    LOADSET(sgB, 1);

    for (int s = 0; s < S; s += 2) {
        CONSUME(sgA);
        if (s + 2 < S) LOADSET(sgA, s + 2);
        lgkm_barrier();
        MFMAPHASE();
        lgkm_barrier();

        CONSUME(sgB);
        if (s + 3 < S) LOADSET(sgB, s + 3);
        lgkm_barrier();
        MFMAPHASE();
        lgkm_barrier();
    }
#undef LOADSET
#undef CONSUME
#undef MFMAPHASE

    // ---- channel sums (reduce over rowgrp lanes) ----
#pragma unroll
    for (int off = 1; off < 4; off <<= 1)
#pragma unroll
        for (int c = 0; c < 4; ++c) ssum[c] += __shfl_xor(ssum[c], off);
    float* sp = Spart + (size_t)(bh * nchunk + chunk) * 512;
    if (qt && (t & 3) == 0 && es == 0)
        *reinterpret_cast<float4*>(&sp[qcq * 4]) = make_float4(ssum[0], ssum[1], ssum[2], ssum[3]);
    if (kt && (kid & 3) == 0)
        *reinterpret_cast<float4*>(&sp[256 + es * 128 + kcq * 4]) =
            make_float4(ssum[0], ssum[1], ssum[2], ssum[3]);

    // ---- Gpart fp16 direct store ----
    unsigned short* gp = Gpart + (size_t)(bh * nchunk + chunk) * 65536;
#pragma unroll
    for (int r = 0; r < 2; ++r)
#pragma unroll
        for (int c = 0; c < 2; ++c)
#pragma unroll
            for (int reg = 0; reg < 16; ++reg) {
                const int de = wr * 64 + r * 32 + (reg & 3) + 8 * (reg >> 2) + 4 * g2;
                const int e  = es * 128 + wc * 64 + c * 32 + l31;
                gp[(size_t)de * 256 + e] = f2h(acc[r][c][reg]);
            }
}

// ---------------------------------------------------------------------------
// Kernel 2: fused chunk-reduce + scores + softmax (both branches) + W/beta.
// Wf row-major [dd][e] bf16.
// ---------------------------------------------------------------------------
__global__ __launch_bounds__(256)
void k_scores(const unsigned short* __restrict__ Gpart, const float* __restrict__ Spart,
              const float* __restrict__ wqg, const float* __restrict__ bqg,
              const float* __restrict__ wkg, const float* __restrict__ bkg,
              const float* __restrict__ wvg, const float* __restrict__ bvg,
              const float* __restrict__ wql, const float* __restrict__ bql,
              const float* __restrict__ wkl, const float* __restrict__ bkl,
              const float* __restrict__ wvl, const float* __restrict__ bvl,
              const float* __restrict__ wp,  const float* __restrict__ bp,
              unsigned short* __restrict__ Wf, float* __restrict__ beta, int nchunk)
{
    __shared__ float sSq[256], sSk[256];
    const int t  = threadIdx.x;
    const int bh = blockIdx.x >> 5;
    const int rg = blockIdx.x & 31;
    const int h  = bh & 3;

    float aq = 0.f, ak = 0.f;
    for (int c = 0; c < nchunk; ++c) {
        const float* sp = Spart + (size_t)(bh * nchunk + c) * 512;
        aq += sp[t]; ak += sp[256 + t];
    }
    sSq[t] = aq; sSk[t] = ak;
    __syncthreads();

    const int dl  = t >> 5;
    const int de  = rg * 8 + dl;
    const int e8  = (t & 31) * 8;
    const int cd  = h * DHEAD + de;
    const int ce0 = h * DHEAD + e8;

    float g[8] = {0.f, 0.f, 0.f, 0.f, 0.f, 0.f, 0.f, 0.f};
    const unsigned short* gpb = Gpart + (size_t)bh * nchunk * 65536 + (size_t)de * 256 + e8;
    for (int c = 0; c < nchunk; ++c) {
        h16x8 v = *reinterpret_cast<const h16x8*>(gpb + (size_t)c * 65536);
#pragma unroll
        for (int j = 0; j < 8; ++j) g[j] += (float)v[j];
    }

    const float sqv = sSq[de];
    float skv[8];
#pragma unroll
    for (int j = 0; j < 8; ++j) skv[j] = sSk[e8 + j];

    float wrow[8] = {0.f, 0.f, 0.f, 0.f, 0.f, 0.f, 0.f, 0.f};
    float bacc = 0.f;
    const float scale = 0.03125f;
#pragma unroll
    for (int br = 0; br < 2; ++br) {
        const float* wq = br ? wql : wqg;  const float* bq = br ? bql : bqg;
        const float* wk = br ? wkl : wkg;  const float* bk = br ? bkl : bkg;
        const float* wv = br ? wvl : wvg;  const float* bv = br ? bvl : bvg;
        const float wqv = wq[cd], bqv = bq[cd];

        float s[8], mm = -1e30f;
#pragma unroll
        for (int j = 0; j < 8; ++j) {
            const float wkv = wk[ce0 + j], bkv = bk[ce0 + j];
            s[j] = scale * (wqv * wkv * g[j] + wqv * bkv * sqv
                            + bqv * wkv * skv[j] + bqv * bkv * 16384.0f);
            mm = fmaxf(mm, s[j]);
        }
#pragma unroll
        for (int off = 16; off; off >>= 1) mm = fmaxf(mm, __shfl_xor(mm, off));
        float p[8], sum = 0.f;
#pragma unroll
        for (int j = 0; j < 8; ++j) { p[j] = __expf(s[j] - mm); sum += p[j]; }
#pragma unroll
        for (int off = 16; off; off >>= 1) sum += __shfl_xor(sum, off);
        const float inv = 1.f / sum;
#pragma unroll
        for (int j = 0; j < 8; ++j) {
            const float a = p[j] * inv;
            wrow[j] += a * wv[ce0 + j];
            bacc    += a * bv[ce0 + j];
        }
    }
    const float wp2 = 2.f * wp[cd];
    u16x8 pw;
#pragma unroll
    for (int j = 0; j < 8; ++j) pw[j] = f2bf(wp2 * wrow[j]);
    *reinterpret_cast<u16x8*>(Wf + (size_t)bh * 65536 + (size_t)de * 256 + e8) = pw;
#pragma unroll
    for (int off = 16; off; off >>= 1) bacc += __shfl_xor(bacc, off);
    if ((t & 31) == 0) beta[bh * 256 + de] = wp2 * bacc + bp[cd];
}

// ---------------------------------------------------------------------------
// Kernel 3: Out[n][dd] = sum_e W[dd][e]*v[n][ce] + beta[dd].  R8 structure
// (no LDS/barriers, direct v reads, Wf L2/L1-hot) widened to 512 thr /
// 256-row tiles: one bh-slice of Wf per CU -> L1 dedups 8 waves' re-reads,
// halving Wf demand vs 128-row tiles.
// ---------------------------------------------------------------------------
__global__ __launch_bounds__(512, 2)
void k_out(const float* __restrict__ v, const unsigned short* __restrict__ Wf,
           const float* __restrict__ beta, float* __restrict__ out)
{
    const int P    = blockIdx.x;
    const int bh   = P & 7;                 // XCD = bh -> Wf slice L2-local
    const int tile = P >> 3;
    const int b    = bh >> 2, h = bh & 3;

    const int t = threadIdx.x;
    const int w = t >> 6, lane = t & 63;
    const int l31 = lane & 31, g2 = lane >> 5;
    const int n0 = tile * 256 + w * 32;

    const float* pv = v + (size_t)(b * NTOK + n0 + l31) * CDIM + h * DHEAD + g2 * 8;
    const unsigned short* pw = Wf + (size_t)bh * 65536 + (size_t)l31 * 256 + g2 * 8;

    f32x4 Aa[2], Ab[2];
    u16x8 Ba[8], Bb[8];

#define LDSTEP(av, bv2, ks) do {                                              \
        av[0] = *reinterpret_cast<const f32x4*>(pv + (ks) * 16);               \
        av[1] = *reinterpret_cast<const f32x4*>(pv + (ks) * 16 + 4);           \
        _Pragma("unroll") for (int dg = 0; dg < 8; ++dg)                       \
            bv2[dg] = *reinterpret_cast<const u16x8*>(pw + (size_t)dg * 8192 + (ks) * 16); \
    } while (0)

    f32x16 acc[8];
#pragma unroll
    for (int dg = 0; dg < 8; ++dg)
#pragma unroll
        for (int j = 0; j < 16; ++j) acc[dg][j] = 0.f;

#define CPSTEP(av, bv2) do {                                                  \
        int4 A;                                                               \
        A.x = cvtpk(av[0][0], av[0][1]); A.y = cvtpk(av[0][2], av[0][3]);     \
        A.z = cvtpk(av[1][0], av[1][1]); A.w = cvtpk(av[1][2], av[1][3]);     \
        const s16x8 fA = __builtin_bit_cast(s16x8, A);                        \
        _Pragma("unroll") for (int dg = 0; dg < 8; ++dg)                      \
            acc[dg] = __builtin_amdgcn_mfma_f32_32x32x16_bf16(                \
                fA, __builtin_bit_cast(s16x8, bv2[dg]), acc[dg], 0, 0, 0);    \
    } while (0)

    LDSTEP(Aa, Ba, 0);
#pragma unroll
    for (int ks = 0; ks < 16; ks += 2) {
        if (ks + 1 < 16) LDSTEP(Ab, Bb, ks + 1);
        CPSTEP(Aa, Ba);
        if (ks + 2 < 16) LDSTEP(Aa, Ba, ks + 2);
        if (ks + 1 < 16) CPSTEP(Ab, Bb);
    }
#undef LDSTEP
#undef CPSTEP

#pragma unroll
    for (int dg = 0; dg < 8; ++dg) {
        const float bb = beta[bh * 256 + dg * 32 + l31];
#pragma unroll
        for (int reg = 0; reg < 16; ++reg) {
            const int row = (reg & 3) + 8 * (reg >> 2) + 4 * g2;
            out[(size_t)(b * NTOK + n0 + row) * CDIM + h * DHEAD + dg * 32 + l31] =
                acc[dg][reg] + bb;
        }
    }
}

// ---------------------------------------------------------------------------
extern "C" void kernel_launch(void* const* d_in, const int* in_sizes, int n_in,
                              void* d_out, int out_size, void* d_ws, size_t ws_size,
                              hipStream_t stream)
{
    const float* q = (const float*)d_in[0];
    const float* k = (const float*)d_in[1];
    const float* v = (const float*)d_in[2];
    const float* wgt[14];
    for (int i = 0; i < 14; ++i) wgt[i] = (const float*)d_in[3 + i];
    float* out = (float*)d_out;

    int nchunk = 32;
    while (nchunk > 1) {
        size_t need = (size_t)8 * nchunk * 65536 * 2   // Gpart fp16
                    + (size_t)8 * nchunk * 512 * 4     // Spart
                    + (size_t)8 * 65536 * 2            // Wf bf16
                    + (size_t)8 * 256 * 4 + 1024;      // beta + slack
        if (need <= ws_size) break;
        nchunk >>= 1;
    }

    char* p = (char*)d_ws;
    unsigned short* Gpart = (unsigned short*)p; p += (size_t)8 * nchunk * 65536 * 2;
    float* Spart = (float*)p;                   p += (size_t)8 * nchunk * 512 * 4;
    unsigned short* Wf = (unsigned short*)p;    p += (size_t)8 * 65536 * 2;
    float* beta  = (float*)p;

    k_gram<<<dim3(16 * nchunk), dim3(512), 0, stream>>>(q, k, Gpart, Spart, nchunk);
    k_scores<<<dim3(8 * 32), dim3(256), 0, stream>>>(
        Gpart, Spart,
        wgt[0], wgt[1], wgt[2], wgt[3], wgt[4], wgt[5],
        wgt[6], wgt[7], wgt[8], wgt[9], wgt[10], wgt[11],
        wgt[12], wgt[13], Wf, beta, nchunk);
    k_out<<<dim3(8 * 64), dim3(512), 0, stream>>>(v, Wf, beta, out);
}

// Round 13
// 193.943 us; speedup vs baseline: 1.2243x; 1.2243x over previous
//
#include <hip/hip_runtime.h>
#include <stdint.h>

#define NTOK 16384
#define CDIM 1024
#define DHEAD 256

typedef short s16x8 __attribute__((ext_vector_type(8)));
typedef unsigned short u16x8 __attribute__((ext_vector_type(8)));
typedef _Float16 h16x8 __attribute__((ext_vector_type(8)));
typedef float f32x4 __attribute__((ext_vector_type(4)));
typedef float f32x16 __attribute__((ext_vector_type(16)));

static __device__ __forceinline__ unsigned short f2bf(float f) {
    union { float f; unsigned u; } x; x.f = f;
    unsigned r = (x.u + 0x7fffu + ((x.u >> 16) & 1u)) >> 16;
    return (unsigned short)r;
}
static __device__ __forceinline__ unsigned short f2h(float f) {
    _Float16 h = (_Float16)f;
    return __builtin_bit_cast(unsigned short, h);
}
static __device__ __forceinline__ unsigned cvtpk(float lo, float hi) {
    unsigned r;
    asm("v_cvt_pk_bf16_f32 %0, %1, %2" : "=v"(r) : "v"(lo), "v"(hi));
    return r;
}
// Barrier ordering LDS only — global loads stay in flight across it (T4).
static __device__ __forceinline__ void lgkm_barrier() {
    asm volatile("s_waitcnt lgkmcnt(0)" ::: "memory");
    __builtin_amdgcn_s_barrier();
}

// ---------------------------------------------------------------------------
// Kernel 1 (= R6, best measured: 101 us): partial Gram G[de][e] over an
// n-chunk + per-channel sums. 512 thr / 8 waves, full 256x256 tile (minimal
// demand: q,k each read once). Load-role split: t<256 q, t>=256 k (8 f32x4
// per thread per 32-row stage, A/B half pipeline keeps loads outstanding
// across both lgkm-only barriers). LDS [ch][32n] bf16, slot^((ch>>1)&3).
// acc[4][8] = 128 AGPR + ~110 arch < 256 cap at launch_bounds(512,2).
// ---------------------------------------------------------------------------
__global__ __launch_bounds__(512, 2)
void k_gram(const float* __restrict__ q, const float* __restrict__ k,
            unsigned short* __restrict__ Gpart, float* __restrict__ Spart, int nchunk)
{
    __shared__ __align__(16) unsigned short ls[2 * DHEAD * 32];   // 32 KB
    unsigned short* lq = ls;
    unsigned short* lk = ls + DHEAD * 32;

    const int t     = threadIdx.x;
    const int bh    = blockIdx.x & 7;
    const int chunk = blockIdx.x >> 3;
    const int b     = bh >> 2, h = bh & 3;
    const int rows  = NTOK / nchunk;    // 512 at nchunk=32
    const int S     = rows >> 5;        // stages of 32 rows
    const int n0c   = chunk * rows;

    const int lane = t & 63, w = t >> 6;
    const int isK  = t >> 8;            // 0: load q, 1: load k
    const int tl   = t & 255;
    const int ng   = tl & 3;            // 4 n-slots of 8 rows
    const int ch0  = (tl >> 2) * 4;     // 64 channel quads
    const int de0  = (w >> 1) * 64;     // 4 row groups
    const int e0   = (w & 1) * 128;     // 2 col groups

    const float* src    = isK ? k : q;
    unsigned short* dst = isK ? lk : lq;
    const float* row0 = src + ((size_t)b * NTOK + n0c + ng * 8) * CDIM + (size_t)h * DHEAD + ch0;

    f32x4 vA[4], vB[4];
#define GL_A(sidx) do { const size_t o_ = (size_t)(sidx) * 32 * CDIM;                \
        _Pragma("unroll") for (int j_ = 0; j_ < 4; ++j_)                              \
            vA[j_] = *reinterpret_cast<const f32x4*>(row0 + o_ + (size_t)j_ * CDIM);   \
        asm volatile("" ::: "memory"); } while (0)
#define GL_B(sidx) do { const size_t o_ = (size_t)(sidx) * 32 * CDIM + 4 * CDIM;     \
        _Pragma("unroll") for (int j_ = 0; j_ < 4; ++j_)                              \
            vB[j_] = *reinterpret_cast<const f32x4*>(row0 + o_ + (size_t)j_ * CDIM);   \
        asm volatile("" ::: "memory"); } while (0)

    GL_A(0);
    GL_B(0);

    float ssum[4] = {0.f, 0.f, 0.f, 0.f};
    f32x4 acc[4][8];
#pragma unroll
    for (int r = 0; r < 4; ++r)
#pragma unroll
        for (int c = 0; c < 8; ++c) acc[r][c] = (f32x4){0.f, 0.f, 0.f, 0.f};

    for (int s = 0; s < S; ++s) {
        // ---- consume half A (rows ng*8+0..3): lower 8B of the 16B slot ----
#pragma unroll
        for (int c = 0; c < 4; ++c) {
            const int ch = ch0 + c;
            ushort4 p;
            p.x = f2bf(vA[0][c]); p.y = f2bf(vA[1][c]);
            p.z = f2bf(vA[2][c]); p.w = f2bf(vA[3][c]);
            ssum[c] += (vA[0][c] + vA[1][c]) + (vA[2][c] + vA[3][c]);
            *reinterpret_cast<ushort4*>(&dst[ch * 32 + ((ng ^ ((ch >> 1) & 3)) * 8)]) = p;
        }
        if (s + 1 < S) GL_A(s + 1);

        // ---- consume half B (rows ng*8+4..7): upper 8B of the slot ----
#pragma unroll
        for (int c = 0; c < 4; ++c) {
            const int ch = ch0 + c;
            ushort4 p;
            p.x = f2bf(vB[0][c]); p.y = f2bf(vB[1][c]);
            p.z = f2bf(vB[2][c]); p.w = f2bf(vB[3][c]);
            ssum[c] += (vB[0][c] + vB[1][c]) + (vB[2][c] + vB[3][c]);
            *reinterpret_cast<ushort4*>(&dst[ch * 32 + ((ng ^ ((ch >> 1) & 3)) * 8) + 4]) = p;
        }
        if (s + 1 < S) GL_B(s + 1);

        lgkm_barrier();

        // ---- MFMA: one K=32 step over the 32 staged rows ----
        {
            s16x8 af[4], bfr[8];
            const int slot = lane >> 4;
#pragma unroll
            for (int r = 0; r < 4; ++r) {
                const int row = de0 + r * 16 + (lane & 15);
                af[r] = *reinterpret_cast<const s16x8*>(&lq[row * 32 + ((slot ^ ((row >> 1) & 3)) * 8)]);
            }
#pragma unroll
            for (int c = 0; c < 8; ++c) {
                const int row = e0 + c * 16 + (lane & 15);
                bfr[c] = *reinterpret_cast<const s16x8*>(&lk[row * 32 + ((slot ^ ((row >> 1) & 3)) * 8)]);
            }
#pragma unroll
            for (int r = 0; r < 4; ++r)
#pragma unroll
                for (int c = 0; c < 8; ++c)
                    acc[r][c] = __builtin_amdgcn_mfma_f32_16x16x32_bf16(af[r], bfr[c], acc[r][c], 0, 0, 0);
        }
        lgkm_barrier();
    }
#undef GL_A
#undef GL_B

    // ---- per-channel partial sums: reduce across the 4-lane ng group ----
#pragma unroll
    for (int off = 1; off < 4; off <<= 1)
#pragma unroll
        for (int c = 0; c < 4; ++c) ssum[c] += __shfl_xor(ssum[c], off);
    if ((lane & 3) == 0) {
        float* sp = Spart + (size_t)(bh * nchunk + chunk) * 512 + isK * 256;
        *reinterpret_cast<float4*>(&sp[ch0]) = make_float4(ssum[0], ssum[1], ssum[2], ssum[3]);
    }

    // ---- Gpart (fp16) via LDS transpose: 4 quarters of 64 de-rows ----
    unsigned short* gp = Gpart + (size_t)(bh * nchunk + chunk) * 65536;
#pragma unroll
    for (int qtr = 0; qtr < 4; ++qtr) {
        if ((w >> 1) == qtr) {
#pragma unroll
            for (int r = 0; r < 4; ++r) {
                const int de_l = r * 16 + (lane >> 4) * 4;
#pragma unroll
                for (int c = 0; c < 8; ++c) {
                    const int e = e0 + c * 16 + (lane & 15);
#pragma unroll
                    for (int reg = 0; reg < 4; ++reg)
                        ls[(de_l + reg) * 256 + e] = f2h(acc[r][c][reg]);
                }
            }
        }
        lgkm_barrier();
#pragma unroll
        for (int i = 0; i < 4; ++i) {
            const int idx = i * 512 + t;
            *reinterpret_cast<u16x8*>(gp + qtr * 16384 + idx * 8) =
                *reinterpret_cast<const u16x8*>(&ls[idx * 8]);
        }
        lgkm_barrier();
    }
}

// ---------------------------------------------------------------------------
// Kernel 2 (= R8): fused chunk-reduce + scores + softmax (both branches) +
// W/beta. Wf row-major [dd][e] bf16.
// ---------------------------------------------------------------------------
__global__ __launch_bounds__(256)
void k_scores(const unsigned short* __restrict__ Gpart, const float* __restrict__ Spart,
              const float* __restrict__ wqg, const float* __restrict__ bqg,
              const float* __restrict__ wkg, const float* __restrict__ bkg,
              const float* __restrict__ wvg, const float* __restrict__ bvg,
              const float* __restrict__ wql, const float* __restrict__ bql,
              const float* __restrict__ wkl, const float* __restrict__ bkl,
              const float* __restrict__ wvl, const float* __restrict__ bvl,
              const float* __restrict__ wp,  const float* __restrict__ bp,
              unsigned short* __restrict__ Wf, float* __restrict__ beta, int nchunk)
{
    __shared__ float sSq[256], sSk[256];
    const int t  = threadIdx.x;
    const int bh = blockIdx.x >> 5;
    const int rg = blockIdx.x & 31;
    const int h  = bh & 3;

    float aq = 0.f, ak = 0.f;
    for (int c = 0; c < nchunk; ++c) {
        const float* sp = Spart + (size_t)(bh * nchunk + c) * 512;
        aq += sp[t]; ak += sp[256 + t];
    }
    sSq[t] = aq; sSk[t] = ak;
    __syncthreads();

    const int dl  = t >> 5;
    const int de  = rg * 8 + dl;
    const int e8  = (t & 31) * 8;
    const int cd  = h * DHEAD + de;
    const int ce0 = h * DHEAD + e8;

    float g[8] = {0.f, 0.f, 0.f, 0.f, 0.f, 0.f, 0.f, 0.f};
    const unsigned short* gpb = Gpart + (size_t)bh * nchunk * 65536 + (size_t)de * 256 + e8;
    for (int c = 0; c < nchunk; ++c) {
        h16x8 v = *reinterpret_cast<const h16x8*>(gpb + (size_t)c * 65536);
#pragma unroll
        for (int j = 0; j < 8; ++j) g[j] += (float)v[j];
    }

    const float sqv = sSq[de];
    float skv[8];
#pragma unroll
    for (int j = 0; j < 8; ++j) skv[j] = sSk[e8 + j];

    float wrow[8] = {0.f, 0.f, 0.f, 0.f, 0.f, 0.f, 0.f, 0.f};
    float bacc = 0.f;
    const float scale = 0.03125f;
#pragma unroll
    for (int br = 0; br < 2; ++br) {
        const float* wq = br ? wql : wqg;  const float* bq = br ? bql : bqg;
        const float* wk = br ? wkl : wkg;  const float* bk = br ? bkl : bkg;
        const float* wv = br ? wvl : wvg;  const float* bv = br ? bvl : bvg;
        const float wqv = wq[cd], bqv = bq[cd];

        float s[8], mm = -1e30f;
#pragma unroll
        for (int j = 0; j < 8; ++j) {
            const float wkv = wk[ce0 + j], bkv = bk[ce0 + j];
            s[j] = scale * (wqv * wkv * g[j] + wqv * bkv * sqv
                            + bqv * wkv * skv[j] + bqv * bkv * 16384.0f);
            mm = fmaxf(mm, s[j]);
        }
#pragma unroll
        for (int off = 16; off; off >>= 1) mm = fmaxf(mm, __shfl_xor(mm, off));
        float p[8], sum = 0.f;
#pragma unroll
        for (int j = 0; j < 8; ++j) { p[j] = __expf(s[j] - mm); sum += p[j]; }
#pragma unroll
        for (int off = 16; off; off >>= 1) sum += __shfl_xor(sum, off);
        const float inv = 1.f / sum;
#pragma unroll
        for (int j = 0; j < 8; ++j) {
            const float a = p[j] * inv;
            wrow[j] += a * wv[ce0 + j];
            bacc    += a * bv[ce0 + j];
        }
    }
    const float wp2 = 2.f * wp[cd];
    u16x8 pw;
#pragma unroll
    for (int j = 0; j < 8; ++j) pw[j] = f2bf(wp2 * wrow[j]);
    *reinterpret_cast<u16x8*>(Wf + (size_t)bh * 65536 + (size_t)de * 256 + e8) = pw;
#pragma unroll
    for (int off = 16; off; off >>= 1) bacc += __shfl_xor(bacc, off);
    if ((t & 31) == 0) beta[bh * 256 + de] = wp2 * bacc + bp[cd];
}

// ---------------------------------------------------------------------------
// Kernel 3 (= R8, best measured): Out[n][dd] = sum_e W[dd][e]*v[n][ce]+beta.
// NO LDS, NO BARRIERS: wave tile 32n x 256dd. A-frag = v rows read directly
// (per-lane 2x f32x4, coalesced). B-frag = Wf[dd][e] bf16 (L2-hot, XCD-pinned
// by bh). acc 128 AGPR + ~110 arch < 256 (2 waves/SIMD).
// ---------------------------------------------------------------------------
__global__ __launch_bounds__(256, 2)
void k_out(const float* __restrict__ v, const unsigned short* __restrict__ Wf,
           const float* __restrict__ beta, float* __restrict__ out)
{
    const int P    = blockIdx.x;
    const int bh   = P & 7;                 // XCD = P%8 -> all tiles of bh co-XCD
    const int tile = P >> 3;
    const int b    = bh >> 2, h = bh & 3;

    const int t = threadIdx.x;
    const int w = t >> 6, lane = t & 63;
    const int l31 = lane & 31, g2 = lane >> 5;
    const int n0 = tile * 128 + w * 32;

    const float* pv = v + (size_t)(b * NTOK + n0 + l31) * CDIM + h * DHEAD + g2 * 8;
    const unsigned short* pw = Wf + (size_t)bh * 65536 + (size_t)l31 * 256 + g2 * 8;

    f32x4 Aa[2], Ab[2];
    u16x8 Ba[8], Bb[8];

#define LDSTEP(av, bv2, ks) do {                                              \
        av[0] = *reinterpret_cast<const f32x4*>(pv + (ks) * 16);               \
        av[1] = *reinterpret_cast<const f32x4*>(pv + (ks) * 16 + 4);           \
        _Pragma("unroll") for (int dg = 0; dg < 8; ++dg)                       \
            bv2[dg] = *reinterpret_cast<const u16x8*>(pw + (size_t)dg * 8192 + (ks) * 16); \
    } while (0)

    f32x16 acc[8];
#pragma unroll
    for (int dg = 0; dg < 8; ++dg)
#pragma unroll
        for (int j = 0; j < 16; ++j) acc[dg][j] = 0.f;

#define CPSTEP(av, bv2) do {                                                  \
        int4 A;                                                               \
        A.x = cvtpk(av[0][0], av[0][1]); A.y = cvtpk(av[0][2], av[0][3]);     \
        A.z = cvtpk(av[1][0], av[1][1]); A.w = cvtpk(av[1][2], av[1][3]);     \
        const s16x8 fA = __builtin_bit_cast(s16x8, A);                        \
        _Pragma("unroll") for (int dg = 0; dg < 8; ++dg)                      \
            acc[dg] = __builtin_amdgcn_mfma_f32_32x32x16_bf16(                \
                fA, __builtin_bit_cast(s16x8, bv2[dg]), acc[dg], 0, 0, 0);    \
    } while (0)

    LDSTEP(Aa, Ba, 0);
#pragma unroll
    for (int ks = 0; ks < 16; ks += 2) {
        if (ks + 1 < 16) LDSTEP(Ab, Bb, ks + 1);
        CPSTEP(Aa, Ba);
        if (ks + 2 < 16) LDSTEP(Aa, Ba, ks + 2);
        if (ks + 1 < 16) CPSTEP(Ab, Bb);
    }
#undef LDSTEP
#undef CPSTEP

    // ---- store: C layout col=l31=dd, row=(reg&3)+8*(reg>>2)+4*g2 = n ----
#pragma unroll
    for (int dg = 0; dg < 8; ++dg) {
        const float bb = beta[bh * 256 + dg * 32 + l31];
#pragma unroll
        for (int reg = 0; reg < 16; ++reg) {
            const int row = (reg & 3) + 8 * (reg >> 2) + 4 * g2;
            out[(size_t)(b * NTOK + n0 + row) * CDIM + h * DHEAD + dg * 32 + l31] =
                acc[dg][reg] + bb;
        }
    }
}

// ---------------------------------------------------------------------------
extern "C" void kernel_launch(void* const* d_in, const int* in_sizes, int n_in,
                              void* d_out, int out_size, void* d_ws, size_t ws_size,
                              hipStream_t stream)
{
    const float* q = (const float*)d_in[0];
    const float* k = (const float*)d_in[1];
    const float* v = (const float*)d_in[2];
    const float* wgt[14];
    for (int i = 0; i < 14; ++i) wgt[i] = (const float*)d_in[3 + i];
    float* out = (float*)d_out;

    int nchunk = 32;
    while (nchunk > 1) {
        size_t need = (size_t)8 * nchunk * 65536 * 2   // Gpart fp16
                    + (size_t)8 * nchunk * 512 * 4     // Spart
                    + (size_t)8 * 65536 * 2            // Wf bf16
                    + (size_t)8 * 256 * 4 + 1024;      // beta + slack
        if (need <= ws_size) break;
        nchunk >>= 1;
    }

    char* p = (char*)d_ws;
    unsigned short* Gpart = (unsigned short*)p; p += (size_t)8 * nchunk * 65536 * 2;
    float* Spart = (float*)p;                   p += (size_t)8 * nchunk * 512 * 4;
    unsigned short* Wf = (unsigned short*)p;    p += (size_t)8 * 65536 * 2;
    float* beta  = (float*)p;

    k_gram<<<dim3(8 * nchunk), dim3(512), 0, stream>>>(q, k, Gpart, Spart, nchunk);
    k_scores<<<dim3(8 * 32), dim3(256), 0, stream>>>(
        Gpart, Spart,
        wgt[0], wgt[1], wgt[2], wgt[3], wgt[4], wgt[5],
        wgt[6], wgt[7], wgt[8], wgt[9], wgt[10], wgt[11],
        wgt[12], wgt[13], Wf, beta, nchunk);
    k_out<<<dim3(8 * 128), dim3(256), 0, stream>>>(v, Wf, beta, out);
}

// Round 15
// 158.802 us; speedup vs baseline: 1.4952x; 1.2213x over previous
//
#include <hip/hip_runtime.h>
#include <stdint.h>

#define NTOK 16384
#define CDIM 1024
#define DHEAD 256

typedef short s16x8 __attribute__((ext_vector_type(8)));
typedef unsigned short u16x8 __attribute__((ext_vector_type(8)));
typedef _Float16 h16x8 __attribute__((ext_vector_type(8)));
typedef float f32x4 __attribute__((ext_vector_type(4)));
typedef float f32x16 __attribute__((ext_vector_type(16)));

static __device__ __forceinline__ unsigned short f2bf(float f) {
    union { float f; unsigned u; } x; x.f = f;
    unsigned r = (x.u + 0x7fffu + ((x.u >> 16) & 1u)) >> 16;
    return (unsigned short)r;
}
static __device__ __forceinline__ unsigned short f2h(float f) {
    _Float16 h = (_Float16)f;
    return __builtin_bit_cast(unsigned short, h);
}
static __device__ __forceinline__ unsigned cvtpk(float lo, float hi) {
    unsigned r;
    asm("v_cvt_pk_bf16_f32 %0, %1, %2" : "=v"(r) : "v"(lo), "v"(hi));
    return r;
}
// Barrier ordering LDS only — global loads stay in flight across it (T4).
static __device__ __forceinline__ void lgkm_barrier() {
    asm volatile("s_waitcnt lgkmcnt(0)" ::: "memory");
    __builtin_amdgcn_s_barrier();
}

// ---------------------------------------------------------------------------
// Kernel 1 (= R13 verbatim, passed post-timing): partial Gram G[de][e] over
// an n-chunk + per-channel sums. 512 thr / 8 waves, full 256x256 tile.
// Load-role split: t<256 q, t>=256 k; A/B half pipeline across lgkm-only
// barriers. LDS [ch][32n] bf16, slot^((ch>>1)&3).
// ---------------------------------------------------------------------------
__global__ __launch_bounds__(512, 2)
void k_gram(const float* __restrict__ q, const float* __restrict__ k,
            unsigned short* __restrict__ Gpart, float* __restrict__ Spart, int nchunk)
{
    __shared__ __align__(16) unsigned short ls[2 * DHEAD * 32];   // 32 KB
    unsigned short* lq = ls;
    unsigned short* lk = ls + DHEAD * 32;

    const int t     = threadIdx.x;
    const int bh    = blockIdx.x & 7;
    const int chunk = blockIdx.x >> 3;
    const int b     = bh >> 2, h = bh & 3;
    const int rows  = NTOK / nchunk;    // 512 at nchunk=32
    const int S     = rows >> 5;        // stages of 32 rows
    const int n0c   = chunk * rows;

    const int lane = t & 63, w = t >> 6;
    const int isK  = t >> 8;            // 0: load q, 1: load k
    const int tl   = t & 255;
    const int ng   = tl & 3;            // 4 n-slots of 8 rows
    const int ch0  = (tl >> 2) * 4;     // 64 channel quads
    const int de0  = (w >> 1) * 64;     // 4 row groups
    const int e0   = (w & 1) * 128;     // 2 col groups

    const float* src    = isK ? k : q;
    unsigned short* dst = isK ? lk : lq;
    const float* row0 = src + ((size_t)b * NTOK + n0c + ng * 8) * CDIM + (size_t)h * DHEAD + ch0;

    f32x4 vA[4], vB[4];
#define GL_A(sidx) do { const size_t o_ = (size_t)(sidx) * 32 * CDIM;                \
        _Pragma("unroll") for (int j_ = 0; j_ < 4; ++j_)                              \
            vA[j_] = *reinterpret_cast<const f32x4*>(row0 + o_ + (size_t)j_ * CDIM);   \
        asm volatile("" ::: "memory"); } while (0)
#define GL_B(sidx) do { const size_t o_ = (size_t)(sidx) * 32 * CDIM + 4 * CDIM;     \
        _Pragma("unroll") for (int j_ = 0; j_ < 4; ++j_)                              \
            vB[j_] = *reinterpret_cast<const f32x4*>(row0 + o_ + (size_t)j_ * CDIM);   \
        asm volatile("" ::: "memory"); } while (0)

    GL_A(0);
    GL_B(0);

    float ssum[4] = {0.f, 0.f, 0.f, 0.f};
    f32x4 acc[4][8];
#pragma unroll
    for (int r = 0; r < 4; ++r)
#pragma unroll
        for (int c = 0; c < 8; ++c) acc[r][c] = (f32x4){0.f, 0.f, 0.f, 0.f};

    for (int s = 0; s < S; ++s) {
#pragma unroll
        for (int c = 0; c < 4; ++c) {
            const int ch = ch0 + c;
            ushort4 p;
            p.x = f2bf(vA[0][c]); p.y = f2bf(vA[1][c]);
            p.z = f2bf(vA[2][c]); p.w = f2bf(vA[3][c]);
            ssum[c] += (vA[0][c] + vA[1][c]) + (vA[2][c] + vA[3][c]);
            *reinterpret_cast<ushort4*>(&dst[ch * 32 + ((ng ^ ((ch >> 1) & 3)) * 8)]) = p;
        }
        if (s + 1 < S) GL_A(s + 1);

#pragma unroll
        for (int c = 0; c < 4; ++c) {
            const int ch = ch0 + c;
            ushort4 p;
            p.x = f2bf(vB[0][c]); p.y = f2bf(vB[1][c]);
            p.z = f2bf(vB[2][c]); p.w = f2bf(vB[3][c]);
            ssum[c] += (vB[0][c] + vB[1][c]) + (vB[2][c] + vB[3][c]);
            *reinterpret_cast<ushort4*>(&dst[ch * 32 + ((ng ^ ((ch >> 1) & 3)) * 8) + 4]) = p;
        }
        if (s + 1 < S) GL_B(s + 1);

        lgkm_barrier();

        {
            s16x8 af[4], bfr[8];
            const int slot = lane >> 4;
#pragma unroll
            for (int r = 0; r < 4; ++r) {
                const int row = de0 + r * 16 + (lane & 15);
                af[r] = *reinterpret_cast<const s16x8*>(&lq[row * 32 + ((slot ^ ((row >> 1) & 3)) * 8)]);
            }
#pragma unroll
            for (int c = 0; c < 8; ++c) {
                const int row = e0 + c * 16 + (lane & 15);
                bfr[c] = *reinterpret_cast<const s16x8*>(&lk[row * 32 + ((slot ^ ((row >> 1) & 3)) * 8)]);
            }
#pragma unroll
            for (int r = 0; r < 4; ++r)
#pragma unroll
                for (int c = 0; c < 8; ++c)
                    acc[r][c] = __builtin_amdgcn_mfma_f32_16x16x32_bf16(af[r], bfr[c], acc[r][c], 0, 0, 0);
        }
        lgkm_barrier();
    }
#undef GL_A
#undef GL_B

#pragma unroll
    for (int off = 1; off < 4; off <<= 1)
#pragma unroll
        for (int c = 0; c < 4; ++c) ssum[c] += __shfl_xor(ssum[c], off);
    if ((lane & 3) == 0) {
        float* sp = Spart + (size_t)(bh * nchunk + chunk) * 512 + isK * 256;
        *reinterpret_cast<float4*>(&sp[ch0]) = make_float4(ssum[0], ssum[1], ssum[2], ssum[3]);
    }

    unsigned short* gp = Gpart + (size_t)(bh * nchunk + chunk) * 65536;
#pragma unroll
    for (int qtr = 0; qtr < 4; ++qtr) {
        if ((w >> 1) == qtr) {
#pragma unroll
            for (int r = 0; r < 4; ++r) {
                const int de_l = r * 16 + (lane >> 4) * 4;
#pragma unroll
                for (int c = 0; c < 8; ++c) {
                    const int e = e0 + c * 16 + (lane & 15);
#pragma unroll
                    for (int reg = 0; reg < 4; ++reg)
                        ls[(de_l + reg) * 256 + e] = f2h(acc[r][c][reg]);
                }
            }
        }
        lgkm_barrier();
#pragma unroll
        for (int i = 0; i < 4; ++i) {
            const int idx = i * 512 + t;
            *reinterpret_cast<u16x8*>(gp + qtr * 16384 + idx * 8) =
                *reinterpret_cast<const u16x8*>(&ls[idx * 8]);
        }
        lgkm_barrier();
    }
}

// ---------------------------------------------------------------------------
// Kernel 2 (= R13 verbatim, passed post-timing): fused chunk-reduce + scores
// + softmax (both branches) + W/beta. Wf row-major [dd][e] bf16.
// ---------------------------------------------------------------------------
__global__ __launch_bounds__(256)
void k_scores(const unsigned short* __restrict__ Gpart, const float* __restrict__ Spart,
              const float* __restrict__ wqg, const float* __restrict__ bqg,
              const float* __restrict__ wkg, const float* __restrict__ bkg,
              const float* __restrict__ wvg, const float* __restrict__ bvg,
              const float* __restrict__ wql, const float* __restrict__ bql,
              const float* __restrict__ wkl, const float* __restrict__ bkl,
              const float* __restrict__ wvl, const float* __restrict__ bvl,
              const float* __restrict__ wp,  const float* __restrict__ bp,
              unsigned short* __restrict__ Wf, float* __restrict__ beta, int nchunk)
{
    __shared__ float sSq[256], sSk[256];
    const int t  = threadIdx.x;
    const int bh = blockIdx.x >> 5;
    const int rg = blockIdx.x & 31;
    const int h  = bh & 3;

    float aq = 0.f, ak = 0.f;
    for (int c = 0; c < nchunk; ++c) {
        const float* sp = Spart + (size_t)(bh * nchunk + c) * 512;
        aq += sp[t]; ak += sp[256 + t];
    }
    sSq[t] = aq; sSk[t] = ak;
    __syncthreads();

    const int dl  = t >> 5;
    const int de  = rg * 8 + dl;
    const int e8  = (t & 31) * 8;
    const int cd  = h * DHEAD + de;
    const int ce0 = h * DHEAD + e8;

    float g[8] = {0.f, 0.f, 0.f, 0.f, 0.f, 0.f, 0.f, 0.f};
    const unsigned short* gpb = Gpart + (size_t)bh * nchunk * 65536 + (size_t)de * 256 + e8;
    for (int c = 0; c < nchunk; ++c) {
        h16x8 v = *reinterpret_cast<const h16x8*>(gpb + (size_t)c * 65536);
#pragma unroll
        for (int j = 0; j < 8; ++j) g[j] += (float)v[j];
    }

    const float sqv = sSq[de];
    float skv[8];
#pragma unroll
    for (int j = 0; j < 8; ++j) skv[j] = sSk[e8 + j];

    float wrow[8] = {0.f, 0.f, 0.f, 0.f, 0.f, 0.f, 0.f, 0.f};
    float bacc = 0.f;
    const float scale = 0.03125f;
#pragma unroll
    for (int br = 0; br < 2; ++br) {
        const float* wq = br ? wql : wqg;  const float* bq = br ? bql : bqg;
        const float* wk = br ? wkl : wkg;  const float* bk = br ? bkl : bkg;
        const float* wv = br ? wvl : wvg;  const float* bv = br ? bvl : bvg;
        const float wqv = wq[cd], bqv = bq[cd];

        float s[8], mm = -1e30f;
#pragma unroll
        for (int j = 0; j < 8; ++j) {
            const float wkv = wk[ce0 + j], bkv = bk[ce0 + j];
            s[j] = scale * (wqv * wkv * g[j] + wqv * bkv * sqv
                            + bqv * wkv * skv[j] + bqv * bkv * 16384.0f);
            mm = fmaxf(mm, s[j]);
        }
#pragma unroll
        for (int off = 16; off; off >>= 1) mm = fmaxf(mm, __shfl_xor(mm, off));
        float p[8], sum = 0.f;
#pragma unroll
        for (int j = 0; j < 8; ++j) { p[j] = __expf(s[j] - mm); sum += p[j]; }
#pragma unroll
        for (int off = 16; off; off >>= 1) sum += __shfl_xor(sum, off);
        const float inv = 1.f / sum;
#pragma unroll
        for (int j = 0; j < 8; ++j) {
            const float a = p[j] * inv;
            wrow[j] += a * wv[ce0 + j];
            bacc    += a * bv[ce0 + j];
        }
    }
    const float wp2 = 2.f * wp[cd];
    u16x8 pw;
#pragma unroll
    for (int j = 0; j < 8; ++j) pw[j] = f2bf(wp2 * wrow[j]);
    *reinterpret_cast<u16x8*>(Wf + (size_t)bh * 65536 + (size_t)de * 256 + e8) = pw;
#pragma unroll
    for (int off = 16; off; off >>= 1) bacc += __shfl_xor(bacc, off);
    if ((t & 31) == 0) beta[bh * 256 + de] = wp2 * bacc + bp[cd];
}

// ---------------------------------------------------------------------------
// Kernel 3: Out[n][dd] = sum_e W[dd][e]*v[n][ce] + beta[dd].
// Fixes R13's bottleneck (B-frags were 8x 512B-lane-stride scatters/step):
// each block stages its 128dd x 256e Wf slice into LDS ONCE (coalesced),
// XOR-swizzled slot^(row&31) so frag ds_read_b128 (lanes = consecutive dd
// rows at 512B stride) spreads across all 32 banks. ONE __syncthreads,
// then barrier-free: A-frags (v rows) direct-global, depth-2 pipelined.
// Block: 256 thr / 4 waves; wave = 32n x 128dd (acc 64 AGPR); block covers
// 128n x 128dd (ddh half). 64KB LDS -> 2 blocks/CU.
// ---------------------------------------------------------------------------
__global__ __launch_bounds__(256, 2)
void k_out(const float* __restrict__ v, const unsigned short* __restrict__ Wf,
           const float* __restrict__ beta, float* __restrict__ out)
{
    __shared__ __align__(16) unsigned short lw[128 * 256];   // 64 KB
    const int P    = blockIdx.x;
    const int bh   = P & 7;                 // XCD pin: all tiles of bh co-XCD
    const int rest = P >> 3;                // 0..255
    const int tile = rest >> 1;             // 0..127
    const int ddh  = rest & 1;              // dd half
    const int b    = bh >> 2, h = bh & 3;
    const int n0   = tile * 128;

    const int t = threadIdx.x;
    const int w = t >> 6, lane = t & 63;
    const int l31 = lane & 31, g2 = lane >> 5;

    // ---- stage Wf slice [128 dd][256 e], swizzled 16B slots ----
    {
        const unsigned short* ws = Wf + (size_t)bh * 65536 + (size_t)(ddh * 128) * 256;
#pragma unroll
        for (int p = 0; p < 16; ++p) {
            const int row = p * 8 + (t >> 5);
            const int c8  = t & 31;
            const u16x8 val = *reinterpret_cast<const u16x8*>(ws + (size_t)row * 256 + c8 * 8);
            *reinterpret_cast<u16x8*>(&lw[row * 256 + ((c8 ^ (row & 31)) * 8)]) = val;
        }
    }
    __syncthreads();

    const float* pv = v + (size_t)(b * NTOK + n0 + w * 32 + l31) * CDIM + h * DHEAD + g2 * 8;

    f32x4 Aa[2], Ab[2];
#define LDSTEP(av, ks) do {                                                   \
        av[0] = *reinterpret_cast<const f32x4*>(pv + (ks) * 16);               \
        av[1] = *reinterpret_cast<const f32x4*>(pv + (ks) * 16 + 4);           \
    } while (0)

    f32x16 acc[4];
#pragma unroll
    for (int dgl = 0; dgl < 4; ++dgl)
#pragma unroll
        for (int j = 0; j < 16; ++j) acc[dgl][j] = 0.f;

#define CPSTEP(av, ks) do {                                                   \
        int4 A;                                                               \
        A.x = cvtpk(av[0][0], av[0][1]); A.y = cvtpk(av[0][2], av[0][3]);     \
        A.z = cvtpk(av[1][0], av[1][1]); A.w = cvtpk(av[1][2], av[1][3]);     \
        const s16x8 fA = __builtin_bit_cast(s16x8, A);                        \
        const int sg = (ks) * 2 + g2;                                         \
        _Pragma("unroll") for (int dgl = 0; dgl < 4; ++dgl) {                 \
            const int row = dgl * 32 + l31;                                   \
            const s16x8 fB = *reinterpret_cast<const s16x8*>(                 \
                &lw[row * 256 + ((sg ^ (row & 31)) * 8)]);                    \
            acc[dgl] = __builtin_amdgcn_mfma_f32_32x32x16_bf16(               \
                fA, fB, acc[dgl], 0, 0, 0);                                   \
        } } while (0)

    LDSTEP(Aa, 0);
#pragma unroll
    for (int ks = 0; ks < 16; ks += 2) {
        if (ks + 1 < 16) LDSTEP(Ab, ks + 1);
        CPSTEP(Aa, ks);
        if (ks + 2 < 16) LDSTEP(Aa, ks + 2);
        if (ks + 1 < 16) CPSTEP(Ab, ks + 1);
    }
#undef LDSTEP
#undef CPSTEP

    // ---- store: col = ddh*128 + dgl*32 + l31, row = (reg&3)+8*(reg>>2)+4*g2 ----
#pragma unroll
    for (int dgl = 0; dgl < 4; ++dgl) {
        const int dd = ddh * 128 + dgl * 32 + l31;
        const float bb = beta[bh * 256 + dd];
#pragma unroll
        for (int reg = 0; reg < 16; ++reg) {
            const int row = (reg & 3) + 8 * (reg >> 2) + 4 * g2;
            out[(size_t)(b * NTOK + n0 + w * 32 + row) * CDIM + h * DHEAD + dd] =
                acc[dgl][reg] + bb;
        }
    }
}

// ---------------------------------------------------------------------------
extern "C" void kernel_launch(void* const* d_in, const int* in_sizes, int n_in,
                              void* d_out, int out_size, void* d_ws, size_t ws_size,
                              hipStream_t stream)
{
    const float* q = (const float*)d_in[0];
    const float* k = (const float*)d_in[1];
    const float* v = (const float*)d_in[2];
    const float* wgt[14];
    for (int i = 0; i < 14; ++i) wgt[i] = (const float*)d_in[3 + i];
    float* out = (float*)d_out;

    int nchunk = 32;
    while (nchunk > 1) {
        size_t need = (size_t)8 * nchunk * 65536 * 2   // Gpart fp16
                    + (size_t)8 * nchunk * 512 * 4     // Spart
                    + (size_t)8 * 65536 * 2            // Wf bf16
                    + (size_t)8 * 256 * 4 + 1024;      // beta + slack
        if (need <= ws_size) break;
        nchunk >>= 1;
    }

    char* p = (char*)d_ws;
    unsigned short* Gpart = (unsigned short*)p; p += (size_t)8 * nchunk * 65536 * 2;
    float* Spart = (float*)p;                   p += (size_t)8 * nchunk * 512 * 4;
    unsigned short* Wf = (unsigned short*)p;    p += (size_t)8 * 65536 * 2;
    float* beta  = (float*)p;

    k_gram<<<dim3(8 * nchunk), dim3(512), 0, stream>>>(q, k, Gpart, Spart, nchunk);
    k_scores<<<dim3(8 * 32), dim3(256), 0, stream>>>(
        Gpart, Spart,
        wgt[0], wgt[1], wgt[2], wgt[3], wgt[4], wgt[5],
        wgt[6], wgt[7], wgt[8], wgt[9], wgt[10], wgt[11],
        wgt[12], wgt[13], Wf, beta, nchunk);
    k_out<<<dim3(8 * 256), dim3(256), 0, stream>>>(v, Wf, beta, out);
}